// Round 7
// baseline (231.636 us; speedup 1.0000x reference)
//
#include <hip/hip_runtime.h>
#include <hip/hip_bf16.h>
#include <math.h>

typedef __attribute__((ext_vector_type(4))) float f32x4;
typedef __attribute__((ext_vector_type(8))) short s16x8;

constexpr int ROWS = 8 * 2048;

__device__ __forceinline__ unsigned short f2bf(float f) {
  unsigned u = __float_as_uint(f);
  return (unsigned short)((u + 0x7fffu + ((u >> 16) & 1u)) >> 16);  // RNE
}
__device__ __forceinline__ float bf2f(unsigned short b) {
  return __uint_as_float(((unsigned)b) << 16);
}

typedef __attribute__((address_space(3))) unsigned u32_lds;
typedef __attribute__((address_space(1))) const unsigned u32_glb;
__device__ __forceinline__ void stage16(const void* g, void* l) {
  __builtin_amdgcn_global_load_lds((u32_glb*)g, (u32_lds*)l, 16, 0, 0);
}

// ---------------------------------------------------------------------------
// k0: prep — split-bf16 W, transposed into MFMA-B-frag layout Wt[(k>>3)][h][k&7]
// ---------------------------------------------------------------------------
__global__ void prep_kernel(const float* __restrict__ W,
                            unsigned short* __restrict__ Wt_hi,
                            unsigned short* __restrict__ Wt_lo) {
  const int id = blockIdx.x * 256 + threadIdx.x;   // k*128+h
  const int k = id >> 7, h = id & 127;
  const float w = W[id];
  const unsigned short hi = f2bf(w);
  const unsigned short lo = f2bf(w - bf2f(hi));
  const int off = ((k >> 3) * 128 + h) * 8 + (k & 7);
  Wt_hi[off] = hi;
  Wt_lo[off] = lo;
}

// ---------------------------------------------------------------------------
// k1: Wh via split-bf16 MFMA. inp AND Wt staged to LDS (coalesced stage16);
// Wt frag reads are ds_read_b128 (kills the scattered L2 reads of R5/R6).
// 128 threads / 2 waves / 32 rows per block; grid 512; 80KB LDS -> 2 blk/CU.
// ---------------------------------------------------------------------------
__global__ __launch_bounds__(128, 2) void whmfma_kernel(
    const float* __restrict__ inp, const unsigned short* __restrict__ Wt_hi,
    const unsigned short* __restrict__ Wt_lo, const float* __restrict__ a,
    unsigned short* __restrict__ Vsw, float* __restrict__ Wh1,
    float* __restrict__ Wh2) {
  __shared__ unsigned short WtH[16][128][8];   // 32KB
  __shared__ unsigned short WtL[16][128][8];   // 32KB
  __shared__ float xl[32][128];                // 16KB (src-swizzled rows)

  const int t = threadIdx.x, w_ = t >> 6, l = t & 63;
  const int lrow = l & 15, kq = l >> 4;
  const int rbase = blockIdx.x * 32;
  const int r0 = rbase + w_ * 16;

  // stage Wt linear: 2048 16B-groups each; wave w_ covers [i*128+w_*64, +64)
#pragma unroll
  for (int i = 0; i < 16; ++i) {
    stage16(Wt_hi + (size_t)(i * 128 + w_ * 64 + l) * 8,
            &WtH[0][0][0] + (size_t)(i * 128 + w_ * 64) * 8);
    stage16(Wt_lo + (size_t)(i * 128 + w_ * 64 + l) * 8,
            &WtL[0][0][0] + (size_t)(i * 128 + w_ * 64) * 8);
  }
  // stage this wave's 16 inp rows (2 rows per stage16), src XOR-swizzled
#pragma unroll
  for (int s = 0; s < 8; ++s) {
    const int rloc = w_ * 16 + 2 * s + (l >> 5);
    stage16(inp + (size_t)(rbase + rloc) * 128 + (((l & 31) ^ (rloc & 7)) << 2),
            &xl[w_ * 16 + 2 * s][0]);
  }
  asm volatile("s_waitcnt vmcnt(0)" ::: "memory");
  __builtin_amdgcn_sched_barrier(0);
  __syncthreads();
  __builtin_amdgcn_sched_barrier(0);

  // A-frags from LDS (swizzled) split to bf16 hi/lo
  s16x8 ahi[4], alo[4];
#pragma unroll
  for (int ks = 0; ks < 4; ++ks) {
    const int g0 = ks * 8 + kq * 2;
    const int sw = lrow & 7;
    const f32x4 x0 = *(const f32x4*)&xl[w_ * 16 + lrow][(g0 ^ sw) << 2];
    const f32x4 x1 = *(const f32x4*)&xl[w_ * 16 + lrow][((g0 + 1) ^ sw) << 2];
    s16x8 th, tl;
#pragma unroll
    for (int e = 0; e < 4; ++e) {
      const unsigned short b0 = f2bf(x0[e]), b1 = f2bf(x1[e]);
      th[e] = (short)b0;       tl[e] = (short)f2bf(x0[e] - bf2f(b0));
      th[4 + e] = (short)b1;   tl[4 + e] = (short)f2bf(x1[e] - bf2f(b1));
    }
    ahi[ks] = th; alo[ks] = tl;
  }

  f32x4 acc[8];
#pragma unroll
  for (int nb = 0; nb < 8; ++nb) acc[nb] = (f32x4){0.f, 0.f, 0.f, 0.f};

#pragma unroll
  for (int ks = 0; ks < 4; ++ks) {
#pragma unroll
    for (int nb = 0; nb < 8; ++nb) {
      const s16x8 bh = *(const s16x8*)&WtH[ks * 4 + kq][nb * 16 + lrow][0];
      const s16x8 bl = *(const s16x8*)&WtL[ks * 4 + kq][nb * 16 + lrow][0];
      acc[nb] = __builtin_amdgcn_mfma_f32_16x16x32_bf16(ahi[ks], bh, acc[nb], 0, 0, 0);
      acc[nb] = __builtin_amdgcn_mfma_f32_16x16x32_bf16(alo[ks], bh, acc[nb], 0, 0, 0);
      acc[nb] = __builtin_amdgcn_mfma_f32_16x16x32_bf16(ahi[ks], bl, acc[nb], 0, 0, 0);
    }
  }

  // Wh1/Wh2 row dots with a1/a2 (h = nb*16+lrow, node = r0 + kq*4 + rg)
  float a1v[8], a2v[8];
#pragma unroll
  for (int nb = 0; nb < 8; ++nb) {
    a1v[nb] = a[nb * 16 + lrow];
    a2v[nb] = a[128 + nb * 16 + lrow];
  }
#pragma unroll
  for (int rg = 0; rg < 4; ++rg) {
    float p1 = 0.f, p2 = 0.f;
#pragma unroll
    for (int nb = 0; nb < 8; ++nb) {
      p1 = fmaf(acc[nb][rg], a1v[nb], p1);
      p2 = fmaf(acc[nb][rg], a2v[nb], p2);
    }
#pragma unroll
    for (int off = 1; off < 16; off <<= 1) {
      p1 += __shfl_xor(p1, off);
      p2 += __shfl_xor(p2, off);
    }
    if (lrow == 0) {
      Wh1[r0 + kq * 4 + rg] = p1;
      Wh2[r0 + kq * 4 + rg] = p2;
    }
  }

  // Vsw[b][jt(32)][jg(8)][h(128)][8j] write
  const int row_g = r0 + kq * 4;
  const int b = row_g >> 11, jt = (row_g >> 6) & 31;
  const int nl0 = row_g & 63, jg = nl0 >> 3, j0 = nl0 & 7;
  unsigned short* __restrict__ vbase = Vsw + (size_t)(b * 32 + jt) * (8 * 128 * 8);
#pragma unroll
  for (int nb = 0; nb < 8; ++nb) {
    unsigned q0, q1;
    asm("v_cvt_pk_bf16_f32 %0, %1, %2" : "=v"(q0) : "v"(acc[nb][0]), "v"(acc[nb][1]));
    asm("v_cvt_pk_bf16_f32 %0, %1, %2" : "=v"(q1) : "v"(acc[nb][2]), "v"(acc[nb][3]));
    *(uint2*)(vbase + ((size_t)jg * 128 + nb * 16 + lrow) * 8 + j0) = make_uint2(q0, q1);
  }
}

// ---------------------------------------------------------------------------
// k2: per-batch max of Wh2 (fixed softmax bound). 8 blocks x 256.
// ---------------------------------------------------------------------------
__global__ void maxred_kernel(const float* __restrict__ Wh2, float* __restrict__ Mh2) {
  __shared__ float ls[4];
  const int b = blockIdx.x, t = threadIdx.x;
  const f32x4* p = (const f32x4*)(Wh2 + (size_t)b * 2048);
  const f32x4 v0 = p[t], v1 = p[t + 256];
  float m = fmaxf(fmaxf(fmaxf(v0[0], v0[1]), fmaxf(v0[2], v0[3])),
                  fmaxf(fmaxf(v1[0], v1[1]), fmaxf(v1[2], v1[3])));
#pragma unroll
  for (int off = 1; off < 64; off <<= 1) m = fmaxf(m, __shfl_xor(m, off));
  if ((t & 63) == 0) ls[t >> 6] = m;
  __syncthreads();
  if (t == 0) Mh2[b] = fmaxf(fmaxf(ls[0], ls[1]), fmaxf(ls[2], ls[3]));
}

// ---------------------------------------------------------------------------
// k3: fused masked softmax (fixed per-row bound) + P@Wh + ELU.
// Counted-vmcnt schedule: per chunk c -> issue V/wv reg loads, vmcnt(16),
// raw s_barrier, stage chunk c+2 (depth-2 Ab prefetch, triple-buffered),
// straight-line body (no cross-lane ops). Wh2 read direct (contiguous, L2).
// ---------------------------------------------------------------------------
__global__ __launch_bounds__(256, 3) void attn_kernel(
    const float* __restrict__ A, const unsigned short* __restrict__ Vsw,
    const float* __restrict__ Wh1, const float* __restrict__ Wh2,
    const float* __restrict__ Mh2, float* __restrict__ out) {
  __shared__ union {
    float Ab[3][16][256];                                                     // 48KB
    struct { float l[64]; float invl[16]; float a4[4][16][132]; } mg;
  } sm;

  const int t = threadIdx.x, w_ = t >> 6, l = t & 63;
  const int lrow = l & 15, lq = l >> 4, g8 = lq * 8;
  const int bid = (blockIdx.x & 7) * 128 + (blockIdx.x >> 3);  // XCD-chunked
  const int b = bid >> 7;
  const int irow = (bid & 127) * 16 + lrow;

  const float* __restrict__ Abase = A + (size_t)bid * 16 * 2048;
  const float* __restrict__ Wh2b = Wh2 + (size_t)b * 2048;
  const float wh1r = Wh1[(size_t)bid * 16 + lrow];
  const unsigned short* __restrict__ Vb = Vsw + (size_t)b * (32 * 8 * 128 * 8);
  const size_t vlane = (size_t)(lq * 128 + lrow) * 8;

  // fixed per-row softmax shift: m >= max_j s_ij (lrelu monotone, mult<=2)
  const float rawu = wh1r + Mh2[b];
  const float lru = fmaxf(rawu, 0.2f * rawu);
  const float m = fmaxf(2.f * lru, lru);

  // prologue: stage chunks 0,1 (wave w_ stages rows w_*4..+3 of each)
#pragma unroll
  for (int cc = 0; cc < 2; ++cc)
#pragma unroll
    for (int rr = 0; rr < 4; ++rr) {
      const int r = w_ * 4 + rr;
      stage16(Abase + (size_t)r * 2048 + cc * 256 + ((l ^ (r & 7)) << 2),
              &sm.Ab[cc][r][0]);
    }

  f32x4 acc[8];
#pragma unroll
  for (int nb = 0; nb < 8; ++nb) acc[nb] = (f32x4){0.f, 0.f, 0.f, 0.f};
  float lsum = 0.f;

  for (int c = 0; c < 8; ++c) {
    const int buf = c % 3;
    const int jb_loc = w_ * 64;
    const int jb_glob = c * 256 + jb_loc;
    const unsigned short* __restrict__ Vt = Vb + (size_t)(c * 4 + w_) * (8 * 128 * 8);

    // issue V first-half (8) + wh2 frags (4) BEFORE the counted wait
    s16x8 v0[4], v1[4];
#pragma unroll
    for (int nb = 0; nb < 4; ++nb) {
      v0[nb] = *(const s16x8*)(Vt + vlane + nb * 128);
      v1[nb] = *(const s16x8*)(Vt + vlane + 4096 + nb * 128);
    }
    f32x4 wv[4];
#pragma unroll
    for (int q = 0; q < 4; ++q)
      wv[q] = *(const f32x4*)(Wh2b + jb_glob + g8 + (q & 1) * 4 + (q >> 1) * 32);

    // allow the 12 loads above + chunk c+1's 4 stages; forces chunk c landed
    asm volatile("s_waitcnt vmcnt(16)" ::: "memory");
    __builtin_amdgcn_sched_barrier(0);
    __builtin_amdgcn_s_barrier();
    __builtin_amdgcn_sched_barrier(0);

    if (c < 6) {   // stage chunk c+2 (buffer last read in chunk c-1)
#pragma unroll
      for (int rr = 0; rr < 4; ++rr) {
        const int r = w_ * 4 + rr;
        stage16(Abase + (size_t)r * 2048 + (c + 2) * 256 + ((l ^ (r & 7)) << 2),
                &sm.Ab[(c + 2) % 3][r][0]);
      }
    }

    // A-frags (swizzled) from LDS
    f32x4 av[4];
    const int c0 = (jb_loc + g8) >> 2;
#pragma unroll
    for (int q = 0; q < 4; ++q) {
      const int cq = c0 + (q & 1) + (q >> 1) * 8;
      av[q] = *(const f32x4*)&sm.Ab[buf][lrow][(cq ^ (lrow & 7)) << 2];
    }

    // scores -> p (fixed m, no cross-lane ops)
    float p[16];
#pragma unroll
    for (int idx = 0; idx < 16; ++idx) {
      const int j = jb_glob + (idx >> 3) * 32 + g8 + (idx & 7);
      const float aval = av[idx >> 2][idx & 3];
      const float raw = wh1r + wv[idx >> 2][idx & 3];
      const float lr = fmaxf(raw, 0.2f * raw);
      const float mult = aval + ((j == irow) ? 1.f : 0.f);
      p[idx] = (mult > 0.f) ? __expf(mult * lr - m) : 0.f;
      lsum += p[idx];
    }

    union { unsigned u[4]; s16x8 v; } pk0, pk1;
#pragma unroll
    for (int q = 0; q < 4; ++q) {
      asm("v_cvt_pk_bf16_f32 %0, %1, %2" : "=v"(pk0.u[q]) : "v"(p[2 * q]), "v"(p[2 * q + 1]));
      asm("v_cvt_pk_bf16_f32 %0, %1, %2" : "=v"(pk1.u[q]) : "v"(p[8 + 2 * q]), "v"(p[9 + 2 * q]));
    }

    // V second half in-body (L2-hot; latency hides under first 8 MFMAs)
    s16x8 v2[4], v3[4];
#pragma unroll
    for (int nb = 0; nb < 4; ++nb) {
      v2[nb] = *(const s16x8*)(Vt + vlane + (nb + 4) * 128);
      v3[nb] = *(const s16x8*)(Vt + vlane + 4096 + (nb + 4) * 128);
    }
#pragma unroll
    for (int nb = 0; nb < 4; ++nb) {
      acc[nb] = __builtin_amdgcn_mfma_f32_16x16x32_bf16(pk0.v, v0[nb], acc[nb], 0, 0, 0);
      acc[nb] = __builtin_amdgcn_mfma_f32_16x16x32_bf16(pk1.v, v1[nb], acc[nb], 0, 0, 0);
    }
#pragma unroll
    for (int nb = 0; nb < 4; ++nb) {
      acc[nb + 4] = __builtin_amdgcn_mfma_f32_16x16x32_bf16(pk0.v, v2[nb], acc[nb + 4], 0, 0, 0);
      acc[nb + 4] = __builtin_amdgcn_mfma_f32_16x16x32_bf16(pk1.v, v3[nb], acc[nb + 4], 0, 0, 0);
    }
  }

  // ---------------- epilogue: merge partial sums (shared m) ----------------
  lsum += __shfl_xor(lsum, 16);
  lsum += __shfl_xor(lsum, 32);
  __syncthreads();   // full barrier before LDS union switch
  if (l < 16) sm.mg.l[w_ * 16 + l] = lsum;
  __syncthreads();
  if (t < 16)
    sm.mg.invl[t] = 1.f / (sm.mg.l[t] + sm.mg.l[16 + t] + sm.mg.l[32 + t] + sm.mg.l[48 + t]);
#pragma unroll
  for (int nb = 0; nb < 8; ++nb)
#pragma unroll
    for (int rg = 0; rg < 4; ++rg)
      sm.mg.a4[w_][lq * 4 + rg][nb * 16 + lrow] = acc[nb][rg];
  __syncthreads();

  const int h = w_ * 32 + (l & 31);
  float* __restrict__ outp = out + (size_t)bid * 16 * 128;
#pragma unroll
  for (int i = 0; i < 8; ++i) {
    const int r = (l >> 5) + 2 * i;
    float v = (sm.mg.a4[0][r][h] + sm.mg.a4[1][r][h] +
               sm.mg.a4[2][r][h] + sm.mg.a4[3][r][h]) * sm.mg.invl[r];
    outp[(size_t)r * 128 + h] = (v > 0.f) ? v : expm1f(v);
  }
}

extern "C" void kernel_launch(void* const* d_in, const int* in_sizes, int n_in,
                              void* d_out, int out_size, void* d_ws, size_t ws_size,
                              hipStream_t stream) {
  const float* inp = (const float*)d_in[0];   // [B,N,H]
  const float* A   = (const float*)d_in[1];   // [B,N,N]
  const float* W   = (const float*)d_in[2];   // [H,H]
  const float* a   = (const float*)d_in[3];   // [2H,1]
  float* out = (float*)d_out;

  char* ws = (char*)d_ws;
  unsigned short* Vsw = (unsigned short*)ws;   ws += (size_t)8 * 32 * 8 * 128 * 8 * 2;  // 4MB
  float* Wh1 = (float*)ws;                     ws += (size_t)ROWS * 4;
  float* Wh2 = (float*)ws;                     ws += (size_t)ROWS * 4;
  unsigned short* Wt_hi = (unsigned short*)ws; ws += 128 * 128 * 2;
  unsigned short* Wt_lo = (unsigned short*)ws; ws += 128 * 128 * 2;
  float* Mh2 = (float*)ws;                     ws += 8 * 4;

  prep_kernel<<<dim3(64), dim3(256), 0, stream>>>(W, Wt_hi, Wt_lo);
  whmfma_kernel<<<dim3(512), dim3(128), 0, stream>>>(inp, Wt_hi, Wt_lo, a, Vsw, Wh1, Wh2);
  maxred_kernel<<<dim3(8), dim3(256), 0, stream>>>(Wh2, Mh2);
  attn_kernel<<<dim3(1024), dim3(256), 0, stream>>>(A, Vsw, Wh1, Wh2, Mh2, out);
}